// Round 1
// baseline (189.660 us; speedup 1.0000x reference)
//
#include <hip/hip_runtime.h>

// Problem constants
#define BATCH 8192
#define INF_  1024   // IN
#define OUTF  1024   // OUT
#define INV_B (1.0f/8192.0f)
#define RATE_C 1e-3f
#define SPLITZ 8     // GEMM2 split-K factor

typedef __bf16 bf16x8 __attribute__((ext_vector_type(8)));
typedef float  f32x4  __attribute__((ext_vector_type(4)));

// fp32 -> bf16 round-to-nearest-even
static __device__ __forceinline__ unsigned short f2bf(float f) {
  unsigned int u = __float_as_uint(f);
  u += 0x7fffu + ((u >> 16) & 1u);
  return (unsigned short)(u >> 16);
}

// ---------------------------------------------------------------------------
// Kernel 1: x (fp32 [B][IN]) -> xb (bf16 [B][IN]) and xT (bf16 [IN][B])
// 64x64 tiles, LDS transpose.
// ---------------------------------------------------------------------------
__global__ __launch_bounds__(256) void k_convert_x(
    const float* __restrict__ x, unsigned short* __restrict__ xb,
    unsigned short* __restrict__ xT) {
  __shared__ unsigned short tl[64][72];
  const int t  = threadIdx.x;
  const int r0 = blockIdx.y * 64;
  const int c0 = blockIdx.x * 64;
  const int rr = t >> 4;         // 0..15
  const int cc = (t & 15) * 4;   // 0..60
#pragma unroll
  for (int p = 0; p < 4; ++p) {
    int r = p * 16 + rr;
    float4 v = *(const float4*)&x[(size_t)(r0 + r) * INF_ + c0 + cc];
    ushort4 h;
    h.x = f2bf(v.x); h.y = f2bf(v.y); h.z = f2bf(v.z); h.w = f2bf(v.w);
    *(ushort4*)&xb[(size_t)(r0 + r) * INF_ + c0 + cc] = h;
    tl[cc + 0][r] = h.x; tl[cc + 1][r] = h.y;
    tl[cc + 2][r] = h.z; tl[cc + 3][r] = h.w;
  }
  __syncthreads();
#pragma unroll
  for (int p = 0; p < 4; ++p) {
    int c = p * 16 + rr;
    ushort4 w = *(const ushort4*)&tl[c][cc];
    *(ushort4*)&xT[(size_t)(c0 + c) * BATCH + r0 + cc] = w;
  }
}

// ---------------------------------------------------------------------------
// Kernel 2: W -> Wb (bf16), and rate[o] = 1e-3*sqrt(|1-||W_o||_2|)
// one block per row
// ---------------------------------------------------------------------------
__global__ __launch_bounds__(256) void k_convert_w(
    const float* __restrict__ W, unsigned short* __restrict__ Wb,
    float* __restrict__ rate) {
  __shared__ float red[256];
  const int t = threadIdx.x;
  const int o = blockIdx.x;
  float4 v = *(const float4*)&W[(size_t)o * INF_ + t * 4];
  ushort4 h;
  h.x = f2bf(v.x); h.y = f2bf(v.y); h.z = f2bf(v.z); h.w = f2bf(v.w);
  *(ushort4*)&Wb[(size_t)o * INF_ + t * 4] = h;
  red[t] = v.x * v.x + v.y * v.y + v.z * v.z + v.w * v.w;
  __syncthreads();
  for (int s = 128; s > 0; s >>= 1) {
    if (t < s) red[t] += red[t + s];
    __syncthreads();
  }
  if (t == 0) {
    float nrm = sqrtf(red[0]);
    rate[o] = RATE_C * sqrtf(fabsf(1.0f - nrm));
  }
}

// ---------------------------------------------------------------------------
// Kernel 3/6: NT bf16 GEMM. A [M][K] row-major (lda), B [N][K] row-major (ldb),
// C[m][n] += sum_k A[m][k]*B[n][k].  128x128 block tile, BK=64, 4 waves each
// computing 64x64 via 4x4 grid of 16x16x32 MFMAs.
// mode 0: C[m*ldc+n] = acc + bias[n]   (GEMM1 -> u)
// mode 1: C[z*1Mi + m*ldc+n] = acc     (GEMM2 split-K partials)
// ---------------------------------------------------------------------------
__global__ __launch_bounds__(256, 2) void k_gemm(
    const unsigned short* __restrict__ A, const unsigned short* __restrict__ B,
    int lda, int ldb, int kChunk, float* __restrict__ C, int ldc,
    const float* __restrict__ bias, int mode) {
  __shared__ unsigned short As[128][72];  // +8 halves pad: 2-way-max frag reads
  __shared__ unsigned short Bs[128][72];
  const int t    = threadIdx.x;
  const int m0   = blockIdx.y * 128;
  const int n0   = blockIdx.x * 128;
  const int k0   = blockIdx.z * kChunk;
  const int lr   = t >> 3;        // staging row 0..31
  const int lc   = (t & 7) * 8;   // staging col (halves)
  const int lane = t & 63;
  const int wave = t >> 6;
  const int wm   = (wave >> 1) * 64;
  const int wn   = (wave & 1) * 64;
  const int fm   = lane & 15;
  const int fk   = (lane >> 4) * 8;

  f32x4 acc[4][4] = {};

  for (int ks = 0; ks < kChunk; ks += 64) {
    const int k = k0 + ks;
#pragma unroll
    for (int r = 0; r < 128; r += 32) {
      *(uint4*)&As[lr + r][lc] =
          *(const uint4*)&A[(size_t)(m0 + lr + r) * lda + k + lc];
      *(uint4*)&Bs[lr + r][lc] =
          *(const uint4*)&B[(size_t)(n0 + lr + r) * ldb + k + lc];
    }
    __syncthreads();
#pragma unroll
    for (int kk = 0; kk < 64; kk += 32) {
      bf16x8 af[4], bf[4];
#pragma unroll
      for (int i = 0; i < 4; ++i)
        af[i] = *(const bf16x8*)&As[wm + i * 16 + fm][kk + fk];
#pragma unroll
      for (int i = 0; i < 4; ++i)
        bf[i] = *(const bf16x8*)&Bs[wn + i * 16 + fm][kk + fk];
#pragma unroll
      for (int mt = 0; mt < 4; ++mt)
#pragma unroll
        for (int nt = 0; nt < 4; ++nt)
          acc[mt][nt] = __builtin_amdgcn_mfma_f32_16x16x32_bf16(
              af[mt], bf[nt], acc[mt][nt], 0, 0, 0);
    }
    __syncthreads();
  }

  // Epilogue. C/D layout (m89-verified): col = lane&15, row = (lane>>4)*4 + reg
  const int er = (lane >> 4) * 4;
  if (mode == 0) {
#pragma unroll
    for (int nt = 0; nt < 4; ++nt) {
      const int n  = n0 + wn + nt * 16 + fm;
      const float bv = bias[n];
#pragma unroll
      for (int mt = 0; mt < 4; ++mt) {
        const int mb = m0 + wm + mt * 16 + er;
#pragma unroll
        for (int r = 0; r < 4; ++r)
          C[(size_t)(mb + r) * ldc + n] = acc[mt][nt][r] + bv;
      }
    }
  } else {
    float* Cp = C + (size_t)blockIdx.z * (1024u * 1024u);
#pragma unroll
    for (int nt = 0; nt < 4; ++nt) {
      const int n = n0 + wn + nt * 16 + fm;
#pragma unroll
      for (int mt = 0; mt < 4; ++mt) {
        const int mb = m0 + wm + mt * 16 + er;
#pragma unroll
        for (int r = 0; r < 4; ++r)
          Cp[(size_t)(mb + r) * ldc + n] = acc[mt][nt][r];
      }
    }
  }
}

// ---------------------------------------------------------------------------
// Kernel 4: per-row stats from approximate (bf16-GEMM) u:
//   rowmax, 1/sumexp, and EXACT argmax: candidates within 0.05 of max get
//   their logit recomputed in fp32 from x,W (bf16 u error sigma ~4e-3; 0.05
//   is ~13 sigma). First-index-wins tie rule matches jnp.argmax.
// ---------------------------------------------------------------------------
__global__ __launch_bounds__(256) void k_row_stats(
    const float* __restrict__ u, const float* __restrict__ x,
    const float* __restrict__ W, float* __restrict__ rowmax,
    float* __restrict__ rowinv, int* __restrict__ rowarg) {
  __shared__ float rv[256];
  __shared__ int   ri[256];
  __shared__ int   cnt;
  __shared__ int   cands[32];
  const int t = threadIdx.x;
  const int b = blockIdx.x;
  if (t == 0) cnt = 0;
  float4 v = *(const float4*)&u[(size_t)b * OUTF + t * 4];
  float mv = v.x; int mi = t * 4;
  if (v.y > mv) { mv = v.y; mi = t * 4 + 1; }
  if (v.z > mv) { mv = v.z; mi = t * 4 + 2; }
  if (v.w > mv) { mv = v.w; mi = t * 4 + 3; }
  rv[t] = mv; ri[t] = mi;
  __syncthreads();
  for (int s = 128; s > 0; s >>= 1) {
    if (t < s) {
      if (rv[t + s] > rv[t] || (rv[t + s] == rv[t] && ri[t + s] < ri[t])) {
        rv[t] = rv[t + s]; ri[t] = ri[t + s];
      }
    }
    __syncthreads();
  }
  const float M    = rv[0];
  const int   argA = ri[0];
  __syncthreads();
  float se = __expf(v.x - M) + __expf(v.y - M) + __expf(v.z - M) + __expf(v.w - M);
  rv[t] = se;
  __syncthreads();
  for (int s = 128; s > 0; s >>= 1) {
    if (t < s) rv[t] += rv[t + s];
    __syncthreads();
  }
  const float total = rv[0];
  // gather candidates (always includes argA itself)
  const float thr = M - 0.05f;
  if (v.x >= thr) { int p = atomicAdd(&cnt, 1); if (p < 32) cands[p] = t * 4; }
  if (v.y >= thr) { int p = atomicAdd(&cnt, 1); if (p < 32) cands[p] = t * 4 + 1; }
  if (v.z >= thr) { int p = atomicAdd(&cnt, 1); if (p < 32) cands[p] = t * 4 + 2; }
  if (v.w >= thr) { int p = atomicAdd(&cnt, 1); if (p < 32) cands[p] = t * 4 + 3; }
  __syncthreads();
  int nc = cnt; if (nc > 32) nc = 32;
  int best = argA;
  if (nc > 1) {
    float4 xv = *(const float4*)&x[(size_t)b * INF_ + t * 4];
    float bv = -3.4e38f; int bi = 0x7fffffff;
    for (int c = 0; c < nc; ++c) {
      const int o = cands[c];
      __syncthreads();  // protect rv reuse across iterations
      float4 wv = *(const float4*)&W[(size_t)o * INF_ + t * 4];
      rv[t] = xv.x * wv.x + xv.y * wv.y + xv.z * wv.z + xv.w * wv.w;
      __syncthreads();
      for (int s = 128; s > 0; s >>= 1) {
        if (t < s) rv[t] += rv[t + s];
        __syncthreads();
      }
      const float ev = rv[0];
      if (ev > bv || (ev == bv && o < bi)) { bv = ev; bi = o; }
    }
    best = bi;
  }
  if (t == 0) {
    rowmax[b] = M;
    rowinv[b] = 1.0f / total;
    rowarg[b] = best;
  }
}

// ---------------------------------------------------------------------------
// Kernel 5: yn = negate_non_maximal(softmax(u)); write ynT (bf16 [OUT][B],
// transposed via LDS) and accumulate s[o] = sum_b yn*u (atomic).
// block: 64 batch rows x 256 outputs.
// ---------------------------------------------------------------------------
__global__ __launch_bounds__(256) void k_yn(
    const float* __restrict__ u, const float* __restrict__ rowmax,
    const float* __restrict__ rowinv, const int* __restrict__ rowarg,
    unsigned short* __restrict__ ynT, float* __restrict__ s) {
  __shared__ unsigned short tile[256][72];
  __shared__ float smax[64], sinv[64];
  __shared__ int   sarg[64];
  const int t  = threadIdx.x;
  const int o0 = blockIdx.x * 256;
  const int b0 = blockIdx.y * 64;
  if (t < 64) {
    smax[t] = rowmax[b0 + t];
    sinv[t] = rowinv[b0 + t];
    sarg[t] = rowarg[b0 + t];
  }
  __syncthreads();
  const int o = o0 + t;
  float sacc = 0.0f;
#pragma unroll 4
  for (int r = 0; r < 64; ++r) {
    float uu  = u[(size_t)(b0 + r) * OUTF + o];
    float ysm = __expf(uu - smax[r]) * sinv[r];
    float yn  = (o == sarg[r]) ? ysm : -ysm;
    sacc += yn * uu;
    tile[t][r] = f2bf(yn);
  }
  atomicAdd(&s[o], sacc);
  __syncthreads();
  // write ynT[o0+row][b0 .. b0+63], 128B contiguous per row
#pragma unroll
  for (int it = 0; it < 8; ++it) {
    const int row = it * 32 + (t >> 3);
    const int seg = (t & 7) * 8;  // halves
    uint4 vv = *(const uint4*)&tile[row][seg];
    *(uint4*)&ynT[(size_t)(o0 + row) * BATCH + b0 + seg] = vv;
  }
}

// ---------------------------------------------------------------------------
// Kernel 7: out[o][i] = rate[o] * (sum_z Cpart[z][o][i]/B - (s[o]/B)*W[o][i])
// ---------------------------------------------------------------------------
__global__ __launch_bounds__(256) void k_final(
    const float* __restrict__ Cp, const float* __restrict__ W,
    const float* __restrict__ s, const float* __restrict__ rate,
    float* __restrict__ out) {
  const int g  = blockIdx.x * 256 + threadIdx.x;
  const int i4 = g * 4;
  const int o  = i4 >> 10;
  float4 c = *(const float4*)&Cp[i4];
#pragma unroll
  for (int z = 1; z < SPLITZ; ++z) {
    float4 cz = *(const float4*)&Cp[(size_t)z * (1024u * 1024u) + i4];
    c.x += cz.x; c.y += cz.y; c.z += cz.z; c.w += cz.w;
  }
  float4 w = *(const float4*)&W[i4];
  const float sb = s[o] * INV_B;
  const float rt = rate[o];
  float4 r;
  r.x = rt * (c.x * INV_B - sb * w.x);
  r.y = rt * (c.y * INV_B - sb * w.y);
  r.z = rt * (c.z * INV_B - sb * w.z);
  r.w = rt * (c.w * INV_B - sb * w.w);
  *(float4*)&out[i4] = r;
}

// ---------------------------------------------------------------------------
// Workspace layout (bytes):
//   0        : u fp32 [8192][1024]  (32 MB) -- REUSED as GEMM2 C_part[8] slices
//   33554432 : xb  bf16 [8192][1024] (16 MB)
//   50331648 : xT  bf16 [1024][8192] (16 MB)
//   67108864 : Wb  bf16 [1024][1024] (2 MB)
//   69206016 : ynT bf16 [1024][8192] (16 MB)
//   85983232 : s     fp32 [1024]
//   85987328 : rate  fp32 [1024]
//   85991424 : rowmax fp32 [8192]
//   86024192 : rowinv fp32 [8192]
//   86056960 : rowarg int  [8192]
//   total ~86.1 MB
// ---------------------------------------------------------------------------
extern "C" void kernel_launch(void* const* d_in, const int* in_sizes, int n_in,
                              void* d_out, int out_size, void* d_ws, size_t ws_size,
                              hipStream_t stream) {
  const float* x    = (const float*)d_in[0];
  const float* W    = (const float*)d_in[1];
  const float* bias = (const float*)d_in[2];
  float* out = (float*)d_out;
  char* ws = (char*)d_ws;

  float*          u    = (float*)(ws + 0);
  unsigned short* xb   = (unsigned short*)(ws + 33554432);
  unsigned short* xT   = (unsigned short*)(ws + 50331648);
  unsigned short* Wb   = (unsigned short*)(ws + 67108864);
  unsigned short* ynT  = (unsigned short*)(ws + 69206016);
  float*          svec = (float*)(ws + 85983232);
  float*          rate = (float*)(ws + 85987328);
  float*          rmax = (float*)(ws + 85991424);
  float*          rinv = (float*)(ws + 86024192);
  int*            rarg = (int*)  (ws + 86056960);

  hipMemsetAsync(svec, 0, OUTF * sizeof(float), stream);

  k_convert_x<<<dim3(16, 128), 256, 0, stream>>>(x, xb, xT);
  k_convert_w<<<dim3(1024), 256, 0, stream>>>(W, Wb, rate);
  // GEMM1: u[b][o] = x@W.T + b   (M=8192, N=1024, K=1024)
  k_gemm<<<dim3(8, 64, 1), 256, 0, stream>>>(xb, Wb, 1024, 1024, 1024,
                                             u, 1024, bias, 0);
  k_row_stats<<<dim3(8192), 256, 0, stream>>>(u, x, W, rmax, rinv, rarg);
  k_yn<<<dim3(4, 128), 256, 0, stream>>>(u, rmax, rinv, rarg, ynT, svec);
  // GEMM2: C[o][i] = yn.T@x   (M=1024, N=1024, K=8192, split-K x8)
  // partials overwrite u (dead after k_yn)
  k_gemm<<<dim3(8, 8, SPLITZ), 256, 0, stream>>>(ynT, xT, 8192, 8192,
                                                 8192 / SPLITZ, u, 1024,
                                                 nullptr, 1);
  k_final<<<dim3(1024), 256, 0, stream>>>(u, W, svec, rate, out);
}

// Round 2
// 178.397 us; speedup vs baseline: 1.0631x; 1.0631x over previous
//
#include <hip/hip_runtime.h>

// Problem constants
#define BATCH 8192
#define INF_  1024   // IN
#define OUTF  1024   // OUT
#define INV_B (1.0f/8192.0f)
#define RATE_C 1e-3f
#define SPLITZ 8     // GEMM2 split-K factor

typedef __bf16 bf16x8 __attribute__((ext_vector_type(8)));
typedef float  f32x4  __attribute__((ext_vector_type(4)));
typedef const __attribute__((address_space(1))) unsigned int* gas_t;
typedef __attribute__((address_space(3))) unsigned int* las_t;

// fp32 -> bf16 round-to-nearest-even
static __device__ __forceinline__ unsigned short f2bf(float f) {
  unsigned int u = __float_as_uint(f);
  u += 0x7fffu + ((u >> 16) & 1u);
  return (unsigned short)(u >> 16);
}

// ---------------------------------------------------------------------------
// Kernel 1: x (fp32 [B][IN]) -> xb (bf16 [B][IN]) and xT (bf16 [IN][B])
// 64x64 tiles, LDS transpose.
// ---------------------------------------------------------------------------
__global__ __launch_bounds__(256) void k_convert_x(
    const float* __restrict__ x, unsigned short* __restrict__ xb,
    unsigned short* __restrict__ xT) {
  __shared__ unsigned short tl[64][72];
  const int t  = threadIdx.x;
  const int r0 = blockIdx.y * 64;
  const int c0 = blockIdx.x * 64;
  const int rr = t >> 4;         // 0..15
  const int cc = (t & 15) * 4;   // 0..60
#pragma unroll
  for (int p = 0; p < 4; ++p) {
    int r = p * 16 + rr;
    float4 v = *(const float4*)&x[(size_t)(r0 + r) * INF_ + c0 + cc];
    ushort4 h;
    h.x = f2bf(v.x); h.y = f2bf(v.y); h.z = f2bf(v.z); h.w = f2bf(v.w);
    *(ushort4*)&xb[(size_t)(r0 + r) * INF_ + c0 + cc] = h;
    tl[cc + 0][r] = h.x; tl[cc + 1][r] = h.y;
    tl[cc + 2][r] = h.z; tl[cc + 3][r] = h.w;
  }
  __syncthreads();
#pragma unroll
  for (int p = 0; p < 4; ++p) {
    int c = p * 16 + rr;
    ushort4 w = *(const ushort4*)&tl[c][cc];
    *(ushort4*)&xT[(size_t)(c0 + c) * BATCH + r0 + cc] = w;
  }
}

// ---------------------------------------------------------------------------
// Kernel 2: W -> Wb (bf16), and rate[o] = 1e-3*sqrt(|1-||W_o||_2|)
// one block per row
// ---------------------------------------------------------------------------
__global__ __launch_bounds__(256) void k_convert_w(
    const float* __restrict__ W, unsigned short* __restrict__ Wb,
    float* __restrict__ rate) {
  __shared__ float red[256];
  const int t = threadIdx.x;
  const int o = blockIdx.x;
  float4 v = *(const float4*)&W[(size_t)o * INF_ + t * 4];
  ushort4 h;
  h.x = f2bf(v.x); h.y = f2bf(v.y); h.z = f2bf(v.z); h.w = f2bf(v.w);
  *(ushort4*)&Wb[(size_t)o * INF_ + t * 4] = h;
  red[t] = v.x * v.x + v.y * v.y + v.z * v.z + v.w * v.w;
  __syncthreads();
  for (int s = 128; s > 0; s >>= 1) {
    if (t < s) red[t] += red[t + s];
    __syncthreads();
  }
  if (t == 0) {
    float nrm = sqrtf(red[0]);
    rate[o] = RATE_C * sqrtf(fabsf(1.0f - nrm));
  }
}

// ---------------------------------------------------------------------------
// Kernel 3/6: NT bf16 GEMM. A [M][K] row-major (lda), B [N][K] row-major (ldb),
// C[m][n] += sum_k A[m][k]*B[n][k].  128x128 block tile, BK=64, 4 waves each
// computing 64x64 via 4x4 grid of 16x16x32 MFMAs.
//
// Staging: m97-style __builtin_amdgcn_global_load_lds width=16 (direct
// global->LDS DMA, no VGPR round-trip). LDS layout is unpadded [128][64]
// halves with XOR chunk swizzle: 16B chunk c of row r lives at chunk
// position c ^ (r&7). Staging is lane-contiguous (HW requirement: LDS dst =
// wave-uniform base + lane*16); fragment ds_read_b128s hit all 32 banks
// (max 2-way aliasing = free, m136).
//
// mode 0: C[m*ldc+n] = acc + bias[n]   (GEMM1 -> u)
// mode 1: C[z*1Mi + m*ldc+n] = acc     (GEMM2 split-K partials)
// ---------------------------------------------------------------------------
__global__ __launch_bounds__(256, 2) void k_gemm(
    const unsigned short* __restrict__ A, const unsigned short* __restrict__ B,
    int lda, int ldb, int kChunk, float* __restrict__ C, int ldc,
    const float* __restrict__ bias, int mode) {
  __shared__ unsigned short As[128 * 64];
  __shared__ unsigned short Bs[128 * 64];
  const int t    = threadIdx.x;
  const int m0   = blockIdx.y * 128;
  const int n0   = blockIdx.x * 128;
  const int k0   = blockIdx.z * kChunk;
  const int lane = t & 63;
  const int wave = t >> 6;
  const int sr   = lane >> 3;                 // row within the wave's 8-row group
  const int scx  = ((lane & 7) ^ sr) * 8;     // swizzled source chunk (halves)
  const int wm   = (wave >> 1) * 64;
  const int wn   = (wave & 1) * 64;
  const int fm   = lane & 15;
  const int fk   = (lane >> 4) * 8;

  f32x4 acc[4][4] = {};

  // wave-uniform LDS bases (HW adds lane*16 bytes)
  const int ldsRow0 = wave * 8;
  const size_t gArow = (size_t)(m0 + ldsRow0 + sr) * lda + scx;
  const size_t gBrow = (size_t)(n0 + ldsRow0 + sr) * ldb + scx;

  for (int ks = 0; ks < kChunk; ks += 64) {
    const int k = k0 + ks;
#pragma unroll
    for (int j = 0; j < 4; ++j) {
      __builtin_amdgcn_global_load_lds(
          (gas_t)&A[gArow + (size_t)j * 32 * lda + k],
          (las_t)&As[(ldsRow0 + j * 32) * 64], 16, 0, 0);
      __builtin_amdgcn_global_load_lds(
          (gas_t)&B[gBrow + (size_t)j * 32 * ldb + k],
          (las_t)&Bs[(ldsRow0 + j * 32) * 64], 16, 0, 0);
    }
    __syncthreads();
#pragma unroll
    for (int kk = 0; kk < 64; kk += 32) {
      bf16x8 af[4], bf[4];
      const int swz = ((((kk + fk) >> 3) ^ (fm & 7)) << 3);
#pragma unroll
      for (int i = 0; i < 4; ++i)
        af[i] = *(const bf16x8*)&As[(wm + i * 16 + fm) * 64 + swz];
#pragma unroll
      for (int i = 0; i < 4; ++i)
        bf[i] = *(const bf16x8*)&Bs[(wn + i * 16 + fm) * 64 + swz];
#pragma unroll
      for (int mt = 0; mt < 4; ++mt)
#pragma unroll
        for (int nt = 0; nt < 4; ++nt)
          acc[mt][nt] = __builtin_amdgcn_mfma_f32_16x16x32_bf16(
              af[mt], bf[nt], acc[mt][nt], 0, 0, 0);
    }
    __syncthreads();
  }

  // Epilogue. C/D layout (m89-verified): col = lane&15, row = (lane>>4)*4 + reg
  const int er = (lane >> 4) * 4;
  if (mode == 0) {
#pragma unroll
    for (int nt = 0; nt < 4; ++nt) {
      const int n  = n0 + wn + nt * 16 + fm;
      const float bv = bias[n];
#pragma unroll
      for (int mt = 0; mt < 4; ++mt) {
        const int mb = m0 + wm + mt * 16 + er;
#pragma unroll
        for (int r = 0; r < 4; ++r)
          C[(size_t)(mb + r) * ldc + n] = acc[mt][nt][r] + bv;
      }
    }
  } else {
    float* Cp = C + (size_t)blockIdx.z * (1024u * 1024u);
#pragma unroll
    for (int nt = 0; nt < 4; ++nt) {
      const int n = n0 + wn + nt * 16 + fm;
#pragma unroll
      for (int mt = 0; mt < 4; ++mt) {
        const int mb = m0 + wm + mt * 16 + er;
#pragma unroll
        for (int r = 0; r < 4; ++r)
          Cp[(size_t)(mb + r) * ldc + n] = acc[mt][nt][r];
      }
    }
  }
}

// ---------------------------------------------------------------------------
// Kernel 4: per-row stats from approximate (bf16-GEMM) u:
//   rowmax, 1/sumexp, and EXACT argmax: candidates within 0.05 of max get
//   their logit recomputed in fp32 from x,W (bf16 u error sigma ~4e-3; 0.05
//   is ~13 sigma). First-index-wins tie rule matches jnp.argmax.
// ---------------------------------------------------------------------------
__global__ __launch_bounds__(256) void k_row_stats(
    const float* __restrict__ u, const float* __restrict__ x,
    const float* __restrict__ W, float* __restrict__ rowmax,
    float* __restrict__ rowinv, int* __restrict__ rowarg) {
  __shared__ float rv[256];
  __shared__ int   ri[256];
  __shared__ int   cnt;
  __shared__ int   cands[32];
  const int t = threadIdx.x;
  const int b = blockIdx.x;
  if (t == 0) cnt = 0;
  float4 v = *(const float4*)&u[(size_t)b * OUTF + t * 4];
  float mv = v.x; int mi = t * 4;
  if (v.y > mv) { mv = v.y; mi = t * 4 + 1; }
  if (v.z > mv) { mv = v.z; mi = t * 4 + 2; }
  if (v.w > mv) { mv = v.w; mi = t * 4 + 3; }
  rv[t] = mv; ri[t] = mi;
  __syncthreads();
  for (int s = 128; s > 0; s >>= 1) {
    if (t < s) {
      if (rv[t + s] > rv[t] || (rv[t + s] == rv[t] && ri[t + s] < ri[t])) {
        rv[t] = rv[t + s]; ri[t] = ri[t + s];
      }
    }
    __syncthreads();
  }
  const float M    = rv[0];
  const int   argA = ri[0];
  __syncthreads();
  float se = __expf(v.x - M) + __expf(v.y - M) + __expf(v.z - M) + __expf(v.w - M);
  rv[t] = se;
  __syncthreads();
  for (int s = 128; s > 0; s >>= 1) {
    if (t < s) rv[t] += rv[t + s];
    __syncthreads();
  }
  const float total = rv[0];
  // gather candidates (always includes argA itself)
  const float thr = M - 0.05f;
  if (v.x >= thr) { int p = atomicAdd(&cnt, 1); if (p < 32) cands[p] = t * 4; }
  if (v.y >= thr) { int p = atomicAdd(&cnt, 1); if (p < 32) cands[p] = t * 4 + 1; }
  if (v.z >= thr) { int p = atomicAdd(&cnt, 1); if (p < 32) cands[p] = t * 4 + 2; }
  if (v.w >= thr) { int p = atomicAdd(&cnt, 1); if (p < 32) cands[p] = t * 4 + 3; }
  __syncthreads();
  int nc = cnt; if (nc > 32) nc = 32;
  int best = argA;
  if (nc > 1) {
    float4 xv = *(const float4*)&x[(size_t)b * INF_ + t * 4];
    float bv = -3.4e38f; int bi = 0x7fffffff;
    for (int c = 0; c < nc; ++c) {
      const int o = cands[c];
      __syncthreads();  // protect rv reuse across iterations
      float4 wv = *(const float4*)&W[(size_t)o * INF_ + t * 4];
      rv[t] = xv.x * wv.x + xv.y * wv.y + xv.z * wv.z + xv.w * wv.w;
      __syncthreads();
      for (int s = 128; s > 0; s >>= 1) {
        if (t < s) rv[t] += rv[t + s];
        __syncthreads();
      }
      const float ev = rv[0];
      if (ev > bv || (ev == bv && o < bi)) { bv = ev; bi = o; }
    }
    best = bi;
  }
  if (t == 0) {
    rowmax[b] = M;
    rowinv[b] = 1.0f / total;
    rowarg[b] = best;
  }
}

// ---------------------------------------------------------------------------
// Kernel 5: yn = negate_non_maximal(softmax(u)); write ynT (bf16 [OUT][B],
// transposed via LDS) and accumulate s[o] = sum_b yn*u (atomic).
// block: 64 batch rows x 256 outputs.
// ---------------------------------------------------------------------------
__global__ __launch_bounds__(256) void k_yn(
    const float* __restrict__ u, const float* __restrict__ rowmax,
    const float* __restrict__ rowinv, const int* __restrict__ rowarg,
    unsigned short* __restrict__ ynT, float* __restrict__ s) {
  __shared__ unsigned short tile[256][72];
  __shared__ float smax[64], sinv[64];
  __shared__ int   sarg[64];
  const int t  = threadIdx.x;
  const int o0 = blockIdx.x * 256;
  const int b0 = blockIdx.y * 64;
  if (t < 64) {
    smax[t] = rowmax[b0 + t];
    sinv[t] = rowinv[b0 + t];
    sarg[t] = rowarg[b0 + t];
  }
  __syncthreads();
  const int o = o0 + t;
  float sacc = 0.0f;
#pragma unroll 4
  for (int r = 0; r < 64; ++r) {
    float uu  = u[(size_t)(b0 + r) * OUTF + o];
    float ysm = __expf(uu - smax[r]) * sinv[r];
    float yn  = (o == sarg[r]) ? ysm : -ysm;
    sacc += yn * uu;
    tile[t][r] = f2bf(yn);
  }
  atomicAdd(&s[o], sacc);
  __syncthreads();
  // write ynT[o0+row][b0 .. b0+63], 128B contiguous per row
#pragma unroll
  for (int it = 0; it < 8; ++it) {
    const int row = it * 32 + (t >> 3);
    const int seg = (t & 7) * 8;  // halves
    uint4 vv = *(const uint4*)&tile[row][seg];
    *(uint4*)&ynT[(size_t)(o0 + row) * BATCH + b0 + seg] = vv;
  }
}

// ---------------------------------------------------------------------------
// Kernel 7: out[o][i] = rate[o] * (sum_z Cpart[z][o][i]/B - (s[o]/B)*W[o][i])
// ---------------------------------------------------------------------------
__global__ __launch_bounds__(256) void k_final(
    const float* __restrict__ Cp, const float* __restrict__ W,
    const float* __restrict__ s, const float* __restrict__ rate,
    float* __restrict__ out) {
  const int g  = blockIdx.x * 256 + threadIdx.x;
  const int i4 = g * 4;
  const int o  = i4 >> 10;
  float4 c = *(const float4*)&Cp[i4];
#pragma unroll
  for (int z = 1; z < SPLITZ; ++z) {
    float4 cz = *(const float4*)&Cp[(size_t)z * (1024u * 1024u) + i4];
    c.x += cz.x; c.y += cz.y; c.z += cz.z; c.w += cz.w;
  }
  float4 w = *(const float4*)&W[i4];
  const float sb = s[o] * INV_B;
  const float rt = rate[o];
  float4 r;
  r.x = rt * (c.x * INV_B - sb * w.x);
  r.y = rt * (c.y * INV_B - sb * w.y);
  r.z = rt * (c.z * INV_B - sb * w.z);
  r.w = rt * (c.w * INV_B - sb * w.w);
  *(float4*)&out[i4] = r;
}

// ---------------------------------------------------------------------------
// Workspace layout (bytes):
//   0        : u fp32 [8192][1024]  (32 MB) -- REUSED as GEMM2 C_part[8] slices
//   33554432 : xb  bf16 [8192][1024] (16 MB)
//   50331648 : xT  bf16 [1024][8192] (16 MB)
//   67108864 : Wb  bf16 [1024][1024] (2 MB)
//   69206016 : ynT bf16 [1024][8192] (16 MB)
//   85983232 : s     fp32 [1024]
//   85987328 : rate  fp32 [1024]
//   85991424 : rowmax fp32 [8192]
//   86024192 : rowinv fp32 [8192]
//   86056960 : rowarg int  [8192]
//   total ~86.1 MB
// ---------------------------------------------------------------------------
extern "C" void kernel_launch(void* const* d_in, const int* in_sizes, int n_in,
                              void* d_out, int out_size, void* d_ws, size_t ws_size,
                              hipStream_t stream) {
  const float* x    = (const float*)d_in[0];
  const float* W    = (const float*)d_in[1];
  const float* bias = (const float*)d_in[2];
  float* out = (float*)d_out;
  char* ws = (char*)d_ws;

  float*          u    = (float*)(ws + 0);
  unsigned short* xb   = (unsigned short*)(ws + 33554432);
  unsigned short* xT   = (unsigned short*)(ws + 50331648);
  unsigned short* Wb   = (unsigned short*)(ws + 67108864);
  unsigned short* ynT  = (unsigned short*)(ws + 69206016);
  float*          svec = (float*)(ws + 85983232);
  float*          rate = (float*)(ws + 85987328);
  float*          rmax = (float*)(ws + 85991424);
  float*          rinv = (float*)(ws + 86024192);
  int*            rarg = (int*)  (ws + 86056960);

  hipMemsetAsync(svec, 0, OUTF * sizeof(float), stream);

  k_convert_x<<<dim3(16, 128), 256, 0, stream>>>(x, xb, xT);
  k_convert_w<<<dim3(1024), 256, 0, stream>>>(W, Wb, rate);
  // GEMM1: u[b][o] = x@W.T + b   (M=8192, N=1024, K=1024)
  k_gemm<<<dim3(8, 64, 1), 256, 0, stream>>>(xb, Wb, 1024, 1024, 1024,
                                             u, 1024, bias, 0);
  k_row_stats<<<dim3(8192), 256, 0, stream>>>(u, x, W, rmax, rinv, rarg);
  k_yn<<<dim3(4, 128), 256, 0, stream>>>(u, rmax, rinv, rarg, ynT, svec);
  // GEMM2: C[o][i] = yn.T@x   (M=1024, N=1024, K=8192, split-K x8)
  // partials overwrite u (dead after k_yn)
  k_gemm<<<dim3(8, 8, SPLITZ), 256, 0, stream>>>(ynT, xT, 8192, 8192,
                                                 8192 / SPLITZ, u, 1024,
                                                 nullptr, 1);
  k_final<<<dim3(1024), 256, 0, stream>>>(u, W, svec, rate, out);
}

// Round 3
// 158.842 us; speedup vs baseline: 1.1940x; 1.1231x over previous
//
#include <hip/hip_runtime.h>

// Problem constants
#define BATCH 8192
#define INF_  1024   // IN
#define OUTF  1024   // OUT
#define INV_B (1.0f/8192.0f)
#define RATE_C 1e-3f
#define SPLITZ 8     // GEMM2 split-K factor

typedef __bf16 bf16x8 __attribute__((ext_vector_type(8)));
typedef float  f32x4  __attribute__((ext_vector_type(4)));
typedef const __attribute__((address_space(1))) unsigned int* gas_t;
typedef __attribute__((address_space(3))) unsigned int* las_t;

// fp32 -> bf16 round-to-nearest-even
static __device__ __forceinline__ unsigned short f2bf(float f) {
  unsigned int u = __float_as_uint(f);
  u += 0x7fffu + ((u >> 16) & 1u);
  return (unsigned short)(u >> 16);
}

// ---------------------------------------------------------------------------
// Kernel 1 (merged): blocks [0,2048): x -> xb (bf16) + xT (bf16, transposed)
//                    blocks [2048,3072): W row -> Wb + rate[o]; svec[o]=0
// ---------------------------------------------------------------------------
__global__ __launch_bounds__(256) void k_convert(
    const float* __restrict__ x, unsigned short* __restrict__ xb,
    unsigned short* __restrict__ xT, const float* __restrict__ W,
    unsigned short* __restrict__ Wb, float* __restrict__ rate,
    float* __restrict__ svec) {
  const int t = threadIdx.x;
  if (blockIdx.x >= 2048) {
    // ---- W convert + rate ----
    __shared__ float red[256];
    const int o = blockIdx.x - 2048;
    float4 v = *(const float4*)&W[(size_t)o * INF_ + t * 4];
    ushort4 h;
    h.x = f2bf(v.x); h.y = f2bf(v.y); h.z = f2bf(v.z); h.w = f2bf(v.w);
    *(ushort4*)&Wb[(size_t)o * INF_ + t * 4] = h;
    red[t] = v.x * v.x + v.y * v.y + v.z * v.z + v.w * v.w;
    __syncthreads();
    for (int s = 128; s > 0; s >>= 1) {
      if (t < s) red[t] += red[t + s];
      __syncthreads();
    }
    if (t == 0) {
      float nrm = sqrtf(red[0]);
      rate[o] = RATE_C * sqrtf(fabsf(1.0f - nrm));
      svec[o] = 0.0f;
    }
    return;
  }
  // ---- x convert + transpose (64x64 tile) ----
  __shared__ unsigned short tl[64][72];
  const int bx = blockIdx.x & 15;        // 16 col-tiles
  const int by = blockIdx.x >> 4;        // 128 row-tiles
  const int r0 = by * 64;
  const int c0 = bx * 64;
  const int rr = t >> 4;         // 0..15
  const int cc = (t & 15) * 4;   // 0..60
#pragma unroll
  for (int p = 0; p < 4; ++p) {
    int r = p * 16 + rr;
    float4 v = *(const float4*)&x[(size_t)(r0 + r) * INF_ + c0 + cc];
    ushort4 h;
    h.x = f2bf(v.x); h.y = f2bf(v.y); h.z = f2bf(v.z); h.w = f2bf(v.w);
    *(ushort4*)&xb[(size_t)(r0 + r) * INF_ + c0 + cc] = h;
    tl[cc + 0][r] = h.x; tl[cc + 1][r] = h.y;
    tl[cc + 2][r] = h.z; tl[cc + 3][r] = h.w;
  }
  __syncthreads();
#pragma unroll
  for (int p = 0; p < 4; ++p) {
    int c = p * 16 + rr;
    ushort4 w = *(const ushort4*)&tl[c][cc];
    *(ushort4*)&xT[(size_t)(c0 + c) * BATCH + r0 + cc] = w;
  }
}

// ---------------------------------------------------------------------------
// Kernel 2/5: NT bf16 GEMM, 128x128 tile, BK=64, global_load_lds width=16
// staging with XOR chunk swizzle (see round 2). 1-D grid of 512 blocks with
// XCD-aware remap (heuristic: XCD = linear_id % 8):
//   mode 0 (GEMM1): by%8 == id%8  -> each XCD caches 8 A-strips (2MB) + full
//                   Wb (2MB) in its 4MB L2.
//   mode 1 (GEMM2): bz == id%8    -> each XCD works one K-slice: 2MB ynT +
//                   2MB xT working set in L2.
// ---------------------------------------------------------------------------
__global__ __launch_bounds__(256, 2) void k_gemm(
    const unsigned short* __restrict__ A, const unsigned short* __restrict__ B,
    int lda, int ldb, int kChunk, float* __restrict__ C, int ldc,
    const float* __restrict__ bias, int mode) {
  __shared__ unsigned short As[128 * 64];
  __shared__ unsigned short Bs[128 * 64];
  const int t  = threadIdx.x;
  const int id = blockIdx.x;
  int bx, by, bz;
  if (mode == 0) {
    by = (id & 7) | ((id >> 6) << 3);  // m-strip; by%8 == id%8 -> same XCD
    bx = (id >> 3) & 7;
    bz = 0;
  } else {
    bz = id & 7;                       // K-slice pinned to XCD
    by = (id >> 3) & 7;
    bx = id >> 6;
  }
  const int m0   = by * 128;
  const int n0   = bx * 128;
  const int k0   = bz * kChunk;
  const int lane = t & 63;
  const int wave = t >> 6;
  const int sr   = lane >> 3;                 // row within the wave's 8-row group
  const int scx  = ((lane & 7) ^ sr) * 8;     // swizzled source chunk (halves)
  const int wm   = (wave >> 1) * 64;
  const int wn   = (wave & 1) * 64;
  const int fm   = lane & 15;
  const int fk   = (lane >> 4) * 8;

  f32x4 acc[4][4] = {};

  // wave-uniform LDS bases (HW adds lane*16 bytes)
  const int ldsRow0 = wave * 8;
  const size_t gArow = (size_t)(m0 + ldsRow0 + sr) * lda + scx;
  const size_t gBrow = (size_t)(n0 + ldsRow0 + sr) * ldb + scx;

  for (int ks = 0; ks < kChunk; ks += 64) {
    const int k = k0 + ks;
#pragma unroll
    for (int j = 0; j < 4; ++j) {
      __builtin_amdgcn_global_load_lds(
          (gas_t)&A[gArow + (size_t)j * 32 * lda + k],
          (las_t)&As[(ldsRow0 + j * 32) * 64], 16, 0, 0);
      __builtin_amdgcn_global_load_lds(
          (gas_t)&B[gBrow + (size_t)j * 32 * ldb + k],
          (las_t)&Bs[(ldsRow0 + j * 32) * 64], 16, 0, 0);
    }
    __syncthreads();
#pragma unroll
    for (int kk = 0; kk < 64; kk += 32) {
      bf16x8 af[4], bf[4];
      const int swz = ((((kk + fk) >> 3) ^ (fm & 7)) << 3);
#pragma unroll
      for (int i = 0; i < 4; ++i)
        af[i] = *(const bf16x8*)&As[(wm + i * 16 + fm) * 64 + swz];
#pragma unroll
      for (int i = 0; i < 4; ++i)
        bf[i] = *(const bf16x8*)&Bs[(wn + i * 16 + fm) * 64 + swz];
#pragma unroll
      for (int mt = 0; mt < 4; ++mt)
#pragma unroll
        for (int nt = 0; nt < 4; ++nt)
          acc[mt][nt] = __builtin_amdgcn_mfma_f32_16x16x32_bf16(
              af[mt], bf[nt], acc[mt][nt], 0, 0, 0);
    }
    __syncthreads();
  }

  // Epilogue. C/D layout (m89-verified): col = lane&15, row = (lane>>4)*4 + reg
  const int er = (lane >> 4) * 4;
  if (mode == 0) {
#pragma unroll
    for (int nt = 0; nt < 4; ++nt) {
      const int n  = n0 + wn + nt * 16 + fm;
      const float bv = bias[n];
#pragma unroll
      for (int mt = 0; mt < 4; ++mt) {
        const int mb = m0 + wm + mt * 16 + er;
#pragma unroll
        for (int r = 0; r < 4; ++r)
          C[(size_t)(mb + r) * ldc + n] = acc[mt][nt][r] + bv;
      }
    }
  } else {
    float* Cp = C + (size_t)bz * (1024u * 1024u);
#pragma unroll
    for (int nt = 0; nt < 4; ++nt) {
      const int n = n0 + wn + nt * 16 + fm;
#pragma unroll
      for (int mt = 0; mt < 4; ++mt) {
        const int mb = m0 + wm + mt * 16 + er;
#pragma unroll
        for (int r = 0; r < 4; ++r)
          Cp[(size_t)(mb + r) * ldc + n] = acc[mt][nt][r];
      }
    }
  }
}

// ---------------------------------------------------------------------------
// Kernel 3: per-row stats, wave-per-row (4 rows/block, 2048 blocks).
// All reductions via __shfl_xor butterflies (no __syncthreads on hot path).
// Exact argmax: candidates within 0.05 of approx max get their logit
// recomputed in fp32 from x,W (bf16 GEMM error sigma ~5e-3; 0.05 ~ 10 sigma).
// First-index-wins tie rule matches jnp.argmax.
// ---------------------------------------------------------------------------
__global__ __launch_bounds__(256) void k_row_stats(
    const float* __restrict__ u, const float* __restrict__ x,
    const float* __restrict__ W, float* __restrict__ rowmax,
    float* __restrict__ rowinv, int* __restrict__ rowarg) {
  __shared__ int cands[4][32];
  __shared__ int cnt[4];
  const int lane = threadIdx.x & 63;
  const int wave = threadIdx.x >> 6;
  const int b    = blockIdx.x * 4 + wave;

  // load this row's 16 columns per lane: o = lane*16 + j
  float a[16];
  const float* up = &u[(size_t)b * OUTF + lane * 16];
#pragma unroll
  for (int j = 0; j < 16; j += 4) {
    float4 v = *(const float4*)&up[j];
    a[j] = v.x; a[j + 1] = v.y; a[j + 2] = v.z; a[j + 3] = v.w;
  }
  // local max/argmax (first wins within scan order)
  float mv = a[0]; int mi = lane * 16;
#pragma unroll
  for (int j = 1; j < 16; ++j)
    if (a[j] > mv) { mv = a[j]; mi = lane * 16 + j; }
  // butterfly max with index tie-break (lower index wins)
#pragma unroll
  for (int off = 1; off < 64; off <<= 1) {
    float ov = __shfl_xor(mv, off);
    int   oi = __shfl_xor(mi, off);
    if (ov > mv || (ov == mv && oi < mi)) { mv = ov; mi = oi; }
  }
  const float M = mv;
  // sum of exp
  float se = 0.0f;
#pragma unroll
  for (int j = 0; j < 16; ++j) se += __expf(a[j] - M);
#pragma unroll
  for (int off = 1; off < 64; off <<= 1) se += __shfl_xor(se, off);

  // candidate gathering
  const float thr = M - 0.05f;
  int ccount = 0;
  unsigned int cflags = 0;
#pragma unroll
  for (int j = 0; j < 16; ++j)
    if (a[j] >= thr) { cflags |= (1u << j); ++ccount; }
  int tot = ccount;
#pragma unroll
  for (int off = 1; off < 64; off <<= 1) tot += __shfl_xor(tot, off);

  int best = mi;
  if (tot > 1) {
    if (lane == 0) cnt[wave] = 0;
    // in-wave lockstep: lane0 write precedes atomics in program order
    for (int j = 0; j < 16; ++j)
      if (cflags & (1u << j)) {
        int p = atomicAdd(&cnt[wave], 1);
        if (p < 32) cands[wave][p] = lane * 16 + j;
      }
    int nc = cnt[wave]; if (nc > 32) nc = 32;
    // exact fp32 recompute of candidate logits
    float xr[16];
    const float* xp = &x[(size_t)b * INF_ + lane * 16];
#pragma unroll
    for (int j = 0; j < 16; j += 4) {
      float4 v = *(const float4*)&xp[j];
      xr[j] = v.x; xr[j + 1] = v.y; xr[j + 2] = v.z; xr[j + 3] = v.w;
    }
    float bv = -3.4e38f; int bi = 0x7fffffff;
    for (int c = 0; c < nc; ++c) {
      const int o = cands[wave][c];
      const float* wp = &W[(size_t)o * INF_ + lane * 16];
      float d = 0.0f;
#pragma unroll
      for (int j = 0; j < 16; j += 4) {
        float4 v = *(const float4*)&wp[j];
        d += xr[j] * v.x + xr[j + 1] * v.y + xr[j + 2] * v.z + xr[j + 3] * v.w;
      }
#pragma unroll
      for (int off = 1; off < 64; off <<= 1) d += __shfl_xor(d, off);
      if (d > bv || (d == bv && o < bi)) { bv = d; bi = o; }
    }
    best = bi;
  }
  if (lane == 0) {
    rowmax[b] = M;
    rowinv[b] = 1.0f / se;
    rowarg[b] = best;
  }
}

// ---------------------------------------------------------------------------
// Kernel 4: yn = negate_non_maximal(softmax(u)); write ynT (bf16 [OUT][B],
// transposed via LDS) and accumulate s[o] = sum_b yn*u (atomic).
// block: 64 batch rows x 256 outputs. yn values packed 8-at-a-time into a
// single ds_write_b128 (row stride 144B: 16B-aligned, start banks spread ->
// minimum-cycle LDS writes; the old per-half writes were 8-way conflicted).
// ---------------------------------------------------------------------------
__global__ __launch_bounds__(256) void k_yn(
    const float* __restrict__ u, const float* __restrict__ rowmax,
    const float* __restrict__ rowinv, const int* __restrict__ rowarg,
    unsigned short* __restrict__ ynT, float* __restrict__ s) {
  __shared__ unsigned short tile[256][72];
  __shared__ float smax[64], sinv[64];
  __shared__ int   sarg[64];
  const int t  = threadIdx.x;
  const int o0 = blockIdx.x * 256;
  const int b0 = blockIdx.y * 64;
  if (t < 64) {
    smax[t] = rowmax[b0 + t];
    sinv[t] = rowinv[b0 + t];
    sarg[t] = rowarg[b0 + t];
  }
  __syncthreads();
  const int o = o0 + t;
  float sacc = 0.0f;
#pragma unroll
  for (int g = 0; g < 8; ++g) {
    uint4 pkv;
    unsigned short* pk = (unsigned short*)&pkv;
#pragma unroll
    for (int j = 0; j < 8; ++j) {
      const int r = g * 8 + j;
      float uu  = u[(size_t)(b0 + r) * OUTF + o];
      float ysm = __expf(uu - smax[r]) * sinv[r];
      float yn  = (o == sarg[r]) ? ysm : -ysm;
      sacc += yn * uu;
      pk[j] = f2bf(yn);
    }
    *(uint4*)&tile[t][g * 8] = pkv;
  }
  atomicAdd(&s[o], sacc);
  __syncthreads();
  // write ynT[o0+row][b0 .. b0+63], 128B contiguous per row
#pragma unroll
  for (int it = 0; it < 8; ++it) {
    const int row = it * 32 + (t >> 3);
    const int seg = (t & 7) * 8;  // halves
    uint4 vv = *(const uint4*)&tile[row][seg];
    *(uint4*)&ynT[(size_t)(o0 + row) * BATCH + b0 + seg] = vv;
  }
}

// ---------------------------------------------------------------------------
// Kernel 6: out[o][i] = rate[o] * (sum_z Cpart[z][o][i]/B - (s[o]/B)*W[o][i])
// ---------------------------------------------------------------------------
__global__ __launch_bounds__(256) void k_final(
    const float* __restrict__ Cp, const float* __restrict__ W,
    const float* __restrict__ s, const float* __restrict__ rate,
    float* __restrict__ out) {
  const int g  = blockIdx.x * 256 + threadIdx.x;
  const int i4 = g * 4;
  const int o  = i4 >> 10;
  float4 c = *(const float4*)&Cp[i4];
#pragma unroll
  for (int z = 1; z < SPLITZ; ++z) {
    float4 cz = *(const float4*)&Cp[(size_t)z * (1024u * 1024u) + i4];
    c.x += cz.x; c.y += cz.y; c.z += cz.z; c.w += cz.w;
  }
  float4 w = *(const float4*)&W[i4];
  const float sb = s[o] * INV_B;
  const float rt = rate[o];
  float4 r;
  r.x = rt * (c.x * INV_B - sb * w.x);
  r.y = rt * (c.y * INV_B - sb * w.y);
  r.z = rt * (c.z * INV_B - sb * w.z);
  r.w = rt * (c.w * INV_B - sb * w.w);
  *(float4*)&out[i4] = r;
}

// ---------------------------------------------------------------------------
// Workspace layout (bytes):
//   0        : u fp32 [8192][1024]  (32 MB) -- REUSED as GEMM2 C_part[8] slices
//   33554432 : xb  bf16 [8192][1024] (16 MB)
//   50331648 : xT  bf16 [1024][8192] (16 MB)
//   67108864 : Wb  bf16 [1024][1024] (2 MB)
//   69206016 : ynT bf16 [1024][8192] (16 MB)
//   85983232 : s     fp32 [1024]
//   85987328 : rate  fp32 [1024]
//   85991424 : rowmax fp32 [8192]
//   86024192 : rowinv fp32 [8192]
//   86056960 : rowarg int  [8192]
//   total ~86.1 MB
// ---------------------------------------------------------------------------
extern "C" void kernel_launch(void* const* d_in, const int* in_sizes, int n_in,
                              void* d_out, int out_size, void* d_ws, size_t ws_size,
                              hipStream_t stream) {
  const float* x    = (const float*)d_in[0];
  const float* W    = (const float*)d_in[1];
  const float* bias = (const float*)d_in[2];
  float* out = (float*)d_out;
  char* ws = (char*)d_ws;

  float*          u    = (float*)(ws + 0);
  unsigned short* xb   = (unsigned short*)(ws + 33554432);
  unsigned short* xT   = (unsigned short*)(ws + 50331648);
  unsigned short* Wb   = (unsigned short*)(ws + 67108864);
  unsigned short* ynT  = (unsigned short*)(ws + 69206016);
  float*          svec = (float*)(ws + 85983232);
  float*          rate = (float*)(ws + 85987328);
  float*          rmax = (float*)(ws + 85991424);
  float*          rinv = (float*)(ws + 86024192);
  int*            rarg = (int*)  (ws + 86056960);

  k_convert<<<dim3(3072), 256, 0, stream>>>(x, xb, xT, W, Wb, rate, svec);
  // GEMM1: u[b][o] = x@W.T + b   (M=8192, N=1024, K=1024), XCD-grouped
  k_gemm<<<dim3(512), 256, 0, stream>>>(xb, Wb, 1024, 1024, 1024,
                                        u, 1024, bias, 0);
  k_row_stats<<<dim3(2048), 256, 0, stream>>>(u, x, W, rmax, rinv, rarg);
  k_yn<<<dim3(4, 128), 256, 0, stream>>>(u, rmax, rinv, rarg, ynT, svec);
  // GEMM2: C[o][i] = yn.T@x   (M=1024, N=1024, K=8192, split-K x8, z->XCD)
  // partials overwrite u (dead after k_yn)
  k_gemm<<<dim3(512), 256, 0, stream>>>(ynT, xT, 8192, 8192,
                                        8192 / SPLITZ, u, 1024,
                                        nullptr, 1);
  k_final<<<dim3(1024), 256, 0, stream>>>(u, W, svec, rate, out);
}

// Round 4
// 156.902 us; speedup vs baseline: 1.2088x; 1.0124x over previous
//
#include <hip/hip_runtime.h>

// Problem constants
#define BATCH 8192
#define INF_  1024   // IN
#define OUTF  1024   // OUT
#define INV_B (1.0f/8192.0f)
#define RATE_C 1e-3f
#define SPLITZ 16    // GEMM2 split-K factor (bf16 partials)

typedef __bf16 bf16x8 __attribute__((ext_vector_type(8)));
typedef float  f32x4  __attribute__((ext_vector_type(4)));
typedef const __attribute__((address_space(1))) unsigned int* gas_t;
typedef __attribute__((address_space(3))) unsigned int* las_t;

// fp32 -> bf16 round-to-nearest-even
static __device__ __forceinline__ unsigned short f2bf(float f) {
  unsigned int u = __float_as_uint(f);
  u += 0x7fffu + ((u >> 16) & 1u);
  return (unsigned short)(u >> 16);
}
static __device__ __forceinline__ float bf2f(unsigned short h) {
  return __uint_as_float(((unsigned int)h) << 16);
}

// ---------------------------------------------------------------------------
// Kernel 1 (merged): blocks [0,2048): x -> xb (bf16) + xT (bf16, transposed)
//                    blocks [2048,3072): W row -> Wb + rate[o]
// Transpose uses packed-uint LDS (2 b-rows per uint, 33-uint pitch):
// write banks (4m+j+r2)%32 ~2-way, read banks (c+k)%32 exactly 2-way — both
// free per m136 (old version had ~16-way-conflicted ds_write_b16 scatter).
// ---------------------------------------------------------------------------
__global__ __launch_bounds__(256) void k_convert(
    const float* __restrict__ x, unsigned short* __restrict__ xb,
    unsigned short* __restrict__ xT, const float* __restrict__ W,
    unsigned short* __restrict__ Wb, float* __restrict__ rate) {
  const int t = threadIdx.x;
  if (blockIdx.x >= 2048) {
    // ---- W convert + rate ----
    __shared__ float red[256];
    const int o = blockIdx.x - 2048;
    float4 v = *(const float4*)&W[(size_t)o * INF_ + t * 4];
    ushort4 h;
    h.x = f2bf(v.x); h.y = f2bf(v.y); h.z = f2bf(v.z); h.w = f2bf(v.w);
    *(ushort4*)&Wb[(size_t)o * INF_ + t * 4] = h;
    red[t] = v.x * v.x + v.y * v.y + v.z * v.z + v.w * v.w;
    __syncthreads();
    for (int s = 128; s > 0; s >>= 1) {
      if (t < s) red[t] += red[t + s];
      __syncthreads();
    }
    if (t == 0) {
      float nrm = sqrtf(red[0]);
      rate[o] = RATE_C * sqrtf(fabsf(1.0f - nrm));
    }
    return;
  }
  // ---- x convert + transpose (64x64 tile) ----
  __shared__ unsigned int t32[64][33];  // [col c][row-pair r2] packed 2x bf16
  const int bx = blockIdx.x & 15;        // 16 col-tiles
  const int by = blockIdx.x >> 4;        // 128 row-tiles
  const int r0 = by * 64;
  const int c0 = bx * 64;
  const int m = t & 15;          // c-group (4 cols)
  const int q = t >> 4;          // 0..15
#pragma unroll
  for (int p = 0; p < 2; ++p) {
    const int r2 = p * 16 + q;   // row-pair 0..31
    const int b  = r0 + 2 * r2;
    float4 v0 = *(const float4*)&x[(size_t)b * INF_ + c0 + 4 * m];
    float4 v1 = *(const float4*)&x[(size_t)(b + 1) * INF_ + c0 + 4 * m];
    ushort4 h0, h1;
    h0.x = f2bf(v0.x); h0.y = f2bf(v0.y); h0.z = f2bf(v0.z); h0.w = f2bf(v0.w);
    h1.x = f2bf(v1.x); h1.y = f2bf(v1.y); h1.z = f2bf(v1.z); h1.w = f2bf(v1.w);
    *(ushort4*)&xb[(size_t)b * INF_ + c0 + 4 * m] = h0;
    *(ushort4*)&xb[(size_t)(b + 1) * INF_ + c0 + 4 * m] = h1;
    t32[4 * m + 0][r2] = (unsigned int)h0.x | ((unsigned int)h1.x << 16);
    t32[4 * m + 1][r2] = (unsigned int)h0.y | ((unsigned int)h1.y << 16);
    t32[4 * m + 2][r2] = (unsigned int)h0.z | ((unsigned int)h1.z << 16);
    t32[4 * m + 3][r2] = (unsigned int)h0.w | ((unsigned int)h1.w << 16);
  }
  __syncthreads();
  const int c  = t >> 2;         // 0..63 output row (column of x)
  const int sg = t & 3;          // 16-b segment
  unsigned int vb[8];
#pragma unroll
  for (int k = 0; k < 8; ++k) vb[k] = t32[c][sg * 8 + k];
  unsigned short* dst = &xT[(size_t)(c0 + c) * BATCH + r0 + sg * 16];
  *(uint4*)&dst[0] = make_uint4(vb[0], vb[1], vb[2], vb[3]);
  *(uint4*)&dst[8] = make_uint4(vb[4], vb[5], vb[6], vb[7]);
}

// ---------------------------------------------------------------------------
// Kernel 2/5: NT bf16 GEMM, 128x128 tile, BK=64, global_load_lds width=16
// staging with XOR chunk swizzle. XCD-aware 1-D grids:
//   mode 0 (GEMM1, 512 blocks): by%8 == id%8 -> each XCD caches 8 A-strips
//     (2MB) + full Wb (2MB) in its L2. fp32 C with bias.
//   mode 1 (GEMM2, 1024 blocks): XCD = id&7 owns ONE 1024-wide b-slice split
//     into two kChunk=512 halves (bz = 2*xcd + half) -> same 4MB L2 working
//     set as splitz-8, but 3 blocks/CU occupancy. bf16 partial slices.
// ---------------------------------------------------------------------------
__global__ __launch_bounds__(256, 3) void k_gemm(
    const unsigned short* __restrict__ A, const unsigned short* __restrict__ B,
    int lda, int ldb, int kChunk, float* __restrict__ C, int ldc,
    const float* __restrict__ bias, int mode) {
  __shared__ unsigned short As[128 * 64];
  __shared__ unsigned short Bs[128 * 64];
  const int t  = threadIdx.x;
  const int id = blockIdx.x;
  int bx, by, bz;
  if (mode == 0) {
    by = (id & 7) | ((id >> 6) << 3);  // m-strip; by%8 == id%8 -> same XCD
    bx = (id >> 3) & 7;
    bz = 0;
  } else {
    bz = ((id & 7) << 1) | ((id >> 3) & 1);  // XCD id&7 owns b-slice, 2 halves
    by = (id >> 4) & 7;
    bx = id >> 7;
  }
  const int m0   = by * 128;
  const int n0   = bx * 128;
  const int k0   = bz * kChunk;
  const int lane = t & 63;
  const int wave = t >> 6;
  const int sr   = lane >> 3;                 // row within the wave's 8-row group
  const int scx  = ((lane & 7) ^ sr) * 8;     // swizzled source chunk (halves)
  const int wm   = (wave >> 1) * 64;
  const int wn   = (wave & 1) * 64;
  const int fm   = lane & 15;
  const int fk   = (lane >> 4) * 8;

  f32x4 acc[4][4] = {};

  // wave-uniform LDS bases (HW adds lane*16 bytes)
  const int ldsRow0 = wave * 8;
  const size_t gArow = (size_t)(m0 + ldsRow0 + sr) * lda + scx;
  const size_t gBrow = (size_t)(n0 + ldsRow0 + sr) * ldb + scx;

  for (int ks = 0; ks < kChunk; ks += 64) {
    const int k = k0 + ks;
#pragma unroll
    for (int j = 0; j < 4; ++j) {
      __builtin_amdgcn_global_load_lds(
          (gas_t)&A[gArow + (size_t)j * 32 * lda + k],
          (las_t)&As[(ldsRow0 + j * 32) * 64], 16, 0, 0);
      __builtin_amdgcn_global_load_lds(
          (gas_t)&B[gBrow + (size_t)j * 32 * ldb + k],
          (las_t)&Bs[(ldsRow0 + j * 32) * 64], 16, 0, 0);
    }
    __syncthreads();
#pragma unroll
    for (int kk = 0; kk < 64; kk += 32) {
      bf16x8 af[4], bf[4];
      const int swz = ((((kk + fk) >> 3) ^ (fm & 7)) << 3);
#pragma unroll
      for (int i = 0; i < 4; ++i)
        af[i] = *(const bf16x8*)&As[(wm + i * 16 + fm) * 64 + swz];
#pragma unroll
      for (int i = 0; i < 4; ++i)
        bf[i] = *(const bf16x8*)&Bs[(wn + i * 16 + fm) * 64 + swz];
#pragma unroll
      for (int mt = 0; mt < 4; ++mt)
#pragma unroll
        for (int nt = 0; nt < 4; ++nt)
          acc[mt][nt] = __builtin_amdgcn_mfma_f32_16x16x32_bf16(
              af[mt], bf[nt], acc[mt][nt], 0, 0, 0);
    }
    __syncthreads();
  }

  // Epilogue. C/D layout (m89-verified): col = lane&15, row = (lane>>4)*4 + reg
  const int er = (lane >> 4) * 4;
  if (mode == 0) {
#pragma unroll
    for (int nt = 0; nt < 4; ++nt) {
      const int n  = n0 + wn + nt * 16 + fm;
      const float bv = bias[n];
#pragma unroll
      for (int mt = 0; mt < 4; ++mt) {
        const int mb = m0 + wm + mt * 16 + er;
#pragma unroll
        for (int r = 0; r < 4; ++r)
          C[(size_t)(mb + r) * ldc + n] = acc[mt][nt][r] + bv;
      }
    }
  } else {
    unsigned short* Cp = (unsigned short*)C + (size_t)bz * (1024u * 1024u);
#pragma unroll
    for (int nt = 0; nt < 4; ++nt) {
      const int n = n0 + wn + nt * 16 + fm;
#pragma unroll
      for (int mt = 0; mt < 4; ++mt) {
        const int mb = m0 + wm + mt * 16 + er;
#pragma unroll
        for (int r = 0; r < 4; ++r)
          Cp[(size_t)(mb + r) * ldc + n] = f2bf(acc[mt][nt][r]);
      }
    }
  }
}

// ---------------------------------------------------------------------------
// Kernel 3: per-row stats, wave-per-row (4 rows/block, 2048 blocks).
// All reductions via __shfl_xor butterflies. Exact argmax: candidates within
// 0.05 of approx max get logits recomputed in fp32 from x,W.
// ---------------------------------------------------------------------------
__global__ __launch_bounds__(256) void k_row_stats(
    const float* __restrict__ u, const float* __restrict__ x,
    const float* __restrict__ W, float* __restrict__ rowmax,
    float* __restrict__ rowinv, int* __restrict__ rowarg) {
  __shared__ int cands[4][32];
  __shared__ int cnt[4];
  const int lane = threadIdx.x & 63;
  const int wave = threadIdx.x >> 6;
  const int b    = blockIdx.x * 4 + wave;

  float a[16];
  const float* up = &u[(size_t)b * OUTF + lane * 16];
#pragma unroll
  for (int j = 0; j < 16; j += 4) {
    float4 v = *(const float4*)&up[j];
    a[j] = v.x; a[j + 1] = v.y; a[j + 2] = v.z; a[j + 3] = v.w;
  }
  float mv = a[0]; int mi = lane * 16;
#pragma unroll
  for (int j = 1; j < 16; ++j)
    if (a[j] > mv) { mv = a[j]; mi = lane * 16 + j; }
#pragma unroll
  for (int off = 1; off < 64; off <<= 1) {
    float ov = __shfl_xor(mv, off);
    int   oi = __shfl_xor(mi, off);
    if (ov > mv || (ov == mv && oi < mi)) { mv = ov; mi = oi; }
  }
  const float M = mv;
  float se = 0.0f;
#pragma unroll
  for (int j = 0; j < 16; ++j) se += __expf(a[j] - M);
#pragma unroll
  for (int off = 1; off < 64; off <<= 1) se += __shfl_xor(se, off);

  const float thr = M - 0.05f;
  int ccount = 0;
  unsigned int cflags = 0;
#pragma unroll
  for (int j = 0; j < 16; ++j)
    if (a[j] >= thr) { cflags |= (1u << j); ++ccount; }
  int tot = ccount;
#pragma unroll
  for (int off = 1; off < 64; off <<= 1) tot += __shfl_xor(tot, off);

  int best = mi;
  if (tot > 1) {
    if (lane == 0) cnt[wave] = 0;
    for (int j = 0; j < 16; ++j)
      if (cflags & (1u << j)) {
        int p = atomicAdd(&cnt[wave], 1);
        if (p < 32) cands[wave][p] = lane * 16 + j;
      }
    int nc = cnt[wave]; if (nc > 32) nc = 32;
    float xr[16];
    const float* xp = &x[(size_t)b * INF_ + lane * 16];
#pragma unroll
    for (int j = 0; j < 16; j += 4) {
      float4 v = *(const float4*)&xp[j];
      xr[j] = v.x; xr[j + 1] = v.y; xr[j + 2] = v.z; xr[j + 3] = v.w;
    }
    float bv = -3.4e38f; int bi = 0x7fffffff;
    for (int c = 0; c < nc; ++c) {
      const int o = cands[wave][c];
      const float* wp = &W[(size_t)o * INF_ + lane * 16];
      float d = 0.0f;
#pragma unroll
      for (int j = 0; j < 16; j += 4) {
        float4 v = *(const float4*)&wp[j];
        d += xr[j] * v.x + xr[j + 1] * v.y + xr[j + 2] * v.z + xr[j + 3] * v.w;
      }
#pragma unroll
      for (int off = 1; off < 64; off <<= 1) d += __shfl_xor(d, off);
      if (d > bv || (d == bv && o < bi)) { bv = d; bi = o; }
    }
    best = bi;
  }
  if (lane == 0) {
    rowmax[b] = M;
    rowinv[b] = 1.0f / se;
    rowarg[b] = best;
  }
}

// ---------------------------------------------------------------------------
// Kernel 4: yn = negate_non_maximal(softmax(u)); write ynT (bf16 [OUT][B],
// transposed via LDS) and PER-BLOCK partial s: s_part[by][o] = sum_b yn*u
// (plain store — replaces 131K global atomics; k_final reduces).
// ---------------------------------------------------------------------------
__global__ __launch_bounds__(256) void k_yn(
    const float* __restrict__ u, const float* __restrict__ rowmax,
    const float* __restrict__ rowinv, const int* __restrict__ rowarg,
    unsigned short* __restrict__ ynT, float* __restrict__ s_part) {
  __shared__ unsigned short tile[256][72];
  __shared__ float smax[64], sinv[64];
  __shared__ int   sarg[64];
  const int t  = threadIdx.x;
  const int o0 = blockIdx.x * 256;
  const int b0 = blockIdx.y * 64;
  if (t < 64) {
    smax[t] = rowmax[b0 + t];
    sinv[t] = rowinv[b0 + t];
    sarg[t] = rowarg[b0 + t];
  }
  __syncthreads();
  const int o = o0 + t;
  float sacc = 0.0f;
#pragma unroll
  for (int g = 0; g < 8; ++g) {
    uint4 pkv;
    unsigned short* pk = (unsigned short*)&pkv;
#pragma unroll
    for (int j = 0; j < 8; ++j) {
      const int r = g * 8 + j;
      float uu  = u[(size_t)(b0 + r) * OUTF + o];
      float ysm = __expf(uu - smax[r]) * sinv[r];
      float yn  = (o == sarg[r]) ? ysm : -ysm;
      sacc += yn * uu;
      pk[j] = f2bf(yn);
    }
    *(uint4*)&tile[t][g * 8] = pkv;
  }
  s_part[(size_t)blockIdx.y * OUTF + o] = sacc;
  __syncthreads();
#pragma unroll
  for (int it = 0; it < 8; ++it) {
    const int row = it * 32 + (t >> 3);
    const int seg = (t & 7) * 8;  // halves
    uint4 vv = *(const uint4*)&tile[row][seg];
    *(uint4*)&ynT[(size_t)(o0 + row) * BATCH + b0 + seg] = vv;
  }
}

// ---------------------------------------------------------------------------
// Kernel 6: block g handles row o=g.
//   sb = (sum_{by} s_part[by][o]) / B
//   out[o][i] = rate[o] * (sum_z bf16 Cpart[z][o][i]/B - sb*W[o][i])
// ---------------------------------------------------------------------------
__global__ __launch_bounds__(256) void k_final(
    const unsigned short* __restrict__ Cp, const float* __restrict__ W,
    const float* __restrict__ s_part, const float* __restrict__ rate,
    float* __restrict__ out) {
  __shared__ float sred[128];
  const int t = threadIdx.x;
  const int o = blockIdx.x;
  if (t < 128) sred[t] = s_part[(size_t)t * OUTF + o];
  __syncthreads();
  for (int s2 = 64; s2 > 0; s2 >>= 1) {
    if (t < s2) sred[t] += sred[t + s2];
    __syncthreads();
  }
  const float sb = sred[0] * INV_B;
  const float rt = rate[o];
  const int i0 = t * 4;
  float cx = 0, cy = 0, cz = 0, cw = 0;
#pragma unroll
  for (int z = 0; z < SPLITZ; ++z) {
    ushort4 h = *(const ushort4*)&Cp[(size_t)z * (1024u * 1024u) +
                                     (size_t)o * INF_ + i0];
    cx += bf2f(h.x); cy += bf2f(h.y); cz += bf2f(h.z); cw += bf2f(h.w);
  }
  float4 w = *(const float4*)&W[(size_t)o * INF_ + i0];
  float4 r;
  r.x = rt * (cx * INV_B - sb * w.x);
  r.y = rt * (cy * INV_B - sb * w.y);
  r.z = rt * (cz * INV_B - sb * w.z);
  r.w = rt * (cw * INV_B - sb * w.w);
  *(float4*)&out[(size_t)o * INF_ + i0] = r;
}

// ---------------------------------------------------------------------------
// Workspace layout (bytes):
//   0        : u fp32 [8192][1024]  (32 MB) -- REUSED as GEMM2 bf16 Cpart[16]
//   33554432 : xb  bf16 [8192][1024] (16 MB)
//   50331648 : xT  bf16 [1024][8192] (16 MB)
//   67108864 : Wb  bf16 [1024][1024] (2 MB)
//   69206016 : ynT bf16 [1024][8192] (16 MB)
//   85983232 : rate  fp32 [1024]
//   85987328 : rowmax fp32 [8192]
//   86020096 : rowinv fp32 [8192]
//   86052864 : rowarg int  [8192]
//   86085632 : s_part fp32 [128][1024] (512 KB)
//   total ~86.6 MB
// ---------------------------------------------------------------------------
extern "C" void kernel_launch(void* const* d_in, const int* in_sizes, int n_in,
                              void* d_out, int out_size, void* d_ws, size_t ws_size,
                              hipStream_t stream) {
  const float* x    = (const float*)d_in[0];
  const float* W    = (const float*)d_in[1];
  const float* bias = (const float*)d_in[2];
  float* out = (float*)d_out;
  char* ws = (char*)d_ws;

  float*          u     = (float*)(ws + 0);
  unsigned short* xb    = (unsigned short*)(ws + 33554432);
  unsigned short* xT    = (unsigned short*)(ws + 50331648);
  unsigned short* Wb    = (unsigned short*)(ws + 67108864);
  unsigned short* ynT   = (unsigned short*)(ws + 69206016);
  float*          rate  = (float*)(ws + 85983232);
  float*          rmax  = (float*)(ws + 85987328);
  float*          rinv  = (float*)(ws + 86020096);
  int*            rarg  = (int*)  (ws + 86052864);
  float*          spart = (float*)(ws + 86085632);

  k_convert<<<dim3(3072), 256, 0, stream>>>(x, xb, xT, W, Wb, rate);
  // GEMM1: u[b][o] = x@W.T + b   (M=8192, N=1024, K=1024), XCD-grouped
  k_gemm<<<dim3(512), 256, 0, stream>>>(xb, Wb, 1024, 1024, 1024,
                                        u, 1024, bias, 0);
  k_row_stats<<<dim3(2048), 256, 0, stream>>>(u, x, W, rmax, rinv, rarg);
  k_yn<<<dim3(4, 128), 256, 0, stream>>>(u, rmax, rinv, rarg, ynT, spart);
  // GEMM2: C[o][i] = yn.T@x   (M=1024, N=1024, K=8192, split-K x16, bf16
  // partials overwrite u region (dead after k_yn))
  k_gemm<<<dim3(1024), 256, 0, stream>>>(ynT, xT, 8192, 8192, 512,
                                         u, 1024, nullptr, 1);
  k_final<<<dim3(1024), 256, 0, stream>>>((const unsigned short*)u, W, spart,
                                          rate, out);
}